// Round 1
// baseline (95.510 us; speedup 1.0000x reference)
//
#include <hip/hip_runtime.h>

#define EMB 128
#define KN 16
#define NREL 32

// Precompute |cos(rela_table[r], rela_table[c])| for all 32x32 pairs.
__global__ void pgra_costab(const float* __restrict__ rela, float* __restrict__ costab) {
    int t = threadIdx.x;
    if (t >= NREL * NREL) return;
    int r = t >> 5, c = t & 31;
    const float* a = rela + r * EMB;
    const float* b = rela + c * EMB;
    float dot = 0.f, na = 0.f, nb = 0.f;
    #pragma unroll 8
    for (int e = 0; e < EMB; ++e) {
        float x = a[e], y = b[e];
        dot = fmaf(x, y, dot);
        na  = fmaf(x, x, na);
        nb  = fmaf(y, y, nb);
    }
    float den = sqrtf(na) * sqrtf(nb) + 1e-8f;
    costab[t] = fabsf(dot / den);
}

__global__ __launch_bounds__(256) void pgra_main(
    const int* __restrict__ node, const int* __restrict__ relation,
    const int* __restrict__ adj_node, const int* __restrict__ adj_rela,
    const float* __restrict__ node_table, const float* __restrict__ proj_table,
    const float* __restrict__ W0, const float* __restrict__ b0,
    const float* __restrict__ W1, const float* __restrict__ b1,
    const float* __restrict__ costab, float* __restrict__ out)
{
    const int b    = blockIdx.x;
    const int tid  = threadIdx.x;     // 0..255
    const int wave = tid >> 6;
    const int lane = tid & 63;

    __shared__ float s_proj[EMB];
    __shared__ float s_cos[NREL];     // costab[r][rel] for this batch's rel
    __shared__ int   s_n1[KN];
    __shared__ int   s_r0[KN];
    __shared__ float s_agg[KN][EMB];  // attention-aggregated, proj-multiplied
    __shared__ float s_h1[KN][EMB];   // tanh(agg @ W0 + b0)
    __shared__ float s_fin[EMB];

    const int n0  = node[b];
    const int rel = relation[b];
    if (tid < EMB)  s_proj[tid] = proj_table[rel * EMB + tid];
    if (tid < NREL) s_cos[tid]  = costab[tid * NREL + rel];
    if (tid < KN) {
        s_n1[tid] = adj_node[n0 * KN + tid];
        s_r0[tid] = adj_rela[n0 * KN + tid];
    }
    __syncthreads();

    // ---- Phase 1: per first-hop neighbor j, attention-aggregate its 16
    // second-hop neighbors. Wave w handles j = 4w .. 4w+3.
    for (int jj = 0; jj < 4; ++jj) {
        const int j  = wave * 4 + jj;
        const int n1 = s_n1[j];
        const int4* n2p = (const int4*)(adj_node + (size_t)n1 * KN);
        const int4* r1p = (const int4*)(adj_rela + (size_t)n1 * KN);
        int   n2[KN];
        float sc[KN];
        #pragma unroll
        for (int q = 0; q < 4; ++q) {
            int4 nn = n2p[q]; int4 rr = r1p[q];
            n2[4*q+0] = nn.x; n2[4*q+1] = nn.y; n2[4*q+2] = nn.z; n2[4*q+3] = nn.w;
            sc[4*q+0] = s_cos[rr.x]; sc[4*q+1] = s_cos[rr.y];
            sc[4*q+2] = s_cos[rr.z]; sc[4*q+3] = s_cos[rr.w];
        }
        float m = sc[0];
        #pragma unroll
        for (int k = 1; k < KN; ++k) m = fmaxf(m, sc[k]);
        float sum = 0.f;
        #pragma unroll
        for (int k = 0; k < KN; ++k) { sc[k] = __expf(sc[k] - m); sum += sc[k]; }
        const float inv = 1.f / sum;

        // each lane owns embedding elements (2*lane, 2*lane+1)
        float ax = 0.f, ay = 0.f;
        #pragma unroll
        for (int k = 0; k < KN; ++k) {
            const float2 v = ((const float2*)(node_table + (size_t)n2[k] * EMB))[lane];
            ax = fmaf(sc[k], v.x, ax);
            ay = fmaf(sc[k], v.y, ay);
        }
        s_agg[j][2*lane]   = ax * inv * s_proj[2*lane];
        s_agg[j][2*lane+1] = ay * inv * s_proj[2*lane+1];
    }
    __syncthreads();

    // ---- Phase 2: batched matvec h1[j] = tanh(agg[j] @ W0 + b0) for all 16 j.
    // thread t: output element e = t&127, j-group = (t>>7)*8 — each W0 element
    // loaded once per j-group (2 groups) instead of once per j (16x).
    {
        const int e  = tid & 127;
        const int jg = (tid >> 7) * 8;
        float acc[8];
        const float bias = b0[e];
        #pragma unroll
        for (int q = 0; q < 8; ++q) acc[q] = bias;
        for (int ee = 0; ee < EMB; ++ee) {
            const float w = W0[ee * EMB + e];
            #pragma unroll
            for (int q = 0; q < 8; ++q) acc[q] = fmaf(s_agg[jg + q][ee], w, acc[q]);
        }
        #pragma unroll
        for (int q = 0; q < 8; ++q) s_h1[jg + q][e] = tanhf(acc[q]);
    }
    __syncthreads();

    // ---- Phase 3: second-level attention over the 16 h1 vectors (scores from r0).
    if (tid < EMB) {
        float sc0[KN];
        float m = -1e30f;
        #pragma unroll
        for (int k = 0; k < KN; ++k) { sc0[k] = s_cos[s_r0[k]]; m = fmaxf(m, sc0[k]); }
        float sum = 0.f;
        #pragma unroll
        for (int k = 0; k < KN; ++k) { sc0[k] = __expf(sc0[k] - m); sum += sc0[k]; }
        const float inv = 1.f / sum;
        float a = 0.f;
        #pragma unroll
        for (int k = 0; k < KN; ++k) a = fmaf(sc0[k], s_h1[k][tid], a);
        s_fin[tid] = a * inv;
    }
    __syncthreads();

    // ---- Phase 4: out = tanh(fin @ W1 + b1)
    if (tid < EMB) {
        float acc = b1[tid];
        for (int ee = 0; ee < EMB; ++ee) acc = fmaf(s_fin[ee], W1[ee * EMB + tid], acc);
        out[(size_t)b * EMB + tid] = tanhf(acc);
    }
}

extern "C" void kernel_launch(void* const* d_in, const int* in_sizes, int n_in,
                              void* d_out, int out_size, void* d_ws, size_t ws_size,
                              hipStream_t stream) {
    const int*   node       = (const int*)d_in[0];
    const int*   relation   = (const int*)d_in[1];
    const int*   adj_node   = (const int*)d_in[2];
    const int*   adj_rela   = (const int*)d_in[3];
    const float* node_table = (const float*)d_in[4];
    const float* rela_table = (const float*)d_in[5];
    const float* proj_table = (const float*)d_in[6];
    const float* W0         = (const float*)d_in[7];
    const float* b0         = (const float*)d_in[8];
    const float* W1         = (const float*)d_in[9];
    const float* b1         = (const float*)d_in[10];
    float* outp   = (float*)d_out;
    float* costab = (float*)d_ws;   // 32*32 floats = 4 KB
    const int B = in_sizes[0];

    hipLaunchKernelGGL(pgra_costab, dim3(1), dim3(1024), 0, stream, rela_table, costab);
    hipLaunchKernelGGL(pgra_main, dim3(B), dim3(256), 0, stream,
                       node, relation, adj_node, adj_rela,
                       node_table, proj_table, W0, b0, W1, b1, costab, outp);
}

// Round 2
// 79.698 us; speedup vs baseline: 1.1984x; 1.1984x over previous
//
#include <hip/hip_runtime.h>

#define EMB 128
#define KN 16
#define NREL 32

// ---------------- costab: |cos(rela[r], rela[c])| for all 32x32 pairs -------
// One wave per (r,c) pair; 256 blocks x 4 waves = 1024 pairs.
__global__ __launch_bounds__(256) void pgra_costab_k(const float* __restrict__ rela,
                                                     float* __restrict__ costab) {
    const int pair = blockIdx.x * 4 + (threadIdx.x >> 6);
    const int lane = threadIdx.x & 63;
    const int r = pair >> 5, c = pair & 31;
    const float2 av = ((const float2*)(rela + (size_t)r * EMB))[lane];
    const float2 bv = ((const float2*)(rela + (size_t)c * EMB))[lane];
    float dot = av.x * bv.x + av.y * bv.y;
    float na  = av.x * av.x + av.y * av.y;
    float nb  = bv.x * bv.x + bv.y * bv.y;
    #pragma unroll
    for (int off = 32; off > 0; off >>= 1) {
        dot += __shfl_xor(dot, off);
        na  += __shfl_xor(na,  off);
        nb  += __shfl_xor(nb,  off);
    }
    if (lane == 0)
        costab[pair] = fabsf(dot / (sqrtf(na) * sqrtf(nb) + 1e-8f));
}

// ---------------- Kernel A: gather + attention-aggregate, one wave per (b,j) ---
// No LDS, no barriers: 32768 independent waves for maximal latency hiding.
__global__ __launch_bounds__(256) void pgra_gather(
    const int* __restrict__ node, const int* __restrict__ relation,
    const int* __restrict__ adj_node, const int* __restrict__ adj_rela,
    const float* __restrict__ node_table, const float* __restrict__ proj_table,
    const float* __restrict__ costab, float* __restrict__ agg, int npair)
{
    const int p = blockIdx.x * 4 + (threadIdx.x >> 6);
    if (p >= npair) return;
    const int lane = threadIdx.x & 63;
    const int b = p >> 4, j = p & 15;

    const int n0  = node[b];
    const int rel = relation[b];
    const int n1  = adj_node[n0 * KN + j];

    const int4* n2p = (const int4*)(adj_node + (size_t)n1 * KN);
    const int4* r1p = (const int4*)(adj_rela + (size_t)n1 * KN);
    int   n2[KN];
    float sc[KN];
    #pragma unroll
    for (int q = 0; q < 4; ++q) {
        const int4 nn = n2p[q];
        const int4 rr = r1p[q];
        n2[4*q+0] = nn.x; n2[4*q+1] = nn.y; n2[4*q+2] = nn.z; n2[4*q+3] = nn.w;
        sc[4*q+0] = costab[rr.x * NREL + rel];
        sc[4*q+1] = costab[rr.y * NREL + rel];
        sc[4*q+2] = costab[rr.z * NREL + rel];
        sc[4*q+3] = costab[rr.w * NREL + rel];
    }
    float m = sc[0];
    #pragma unroll
    for (int k = 1; k < KN; ++k) m = fmaxf(m, sc[k]);
    float sum = 0.f;
    #pragma unroll
    for (int k = 0; k < KN; ++k) { sc[k] = __expf(sc[k] - m); sum += sc[k]; }
    const float inv = 1.f / sum;

    float ax = 0.f, ay = 0.f;
    #pragma unroll
    for (int k = 0; k < KN; ++k) {
        const float2 v = ((const float2*)(node_table + (size_t)n2[k] * EMB))[lane];
        ax = fmaf(sc[k], v.x, ax);
        ay = fmaf(sc[k], v.y, ay);
    }
    const float2 pj = ((const float2*)(proj_table + (size_t)rel * EMB))[lane];
    float2 o;
    o.x = ax * inv * pj.x;
    o.y = ay * inv * pj.y;
    ((float2*)(agg + (size_t)p * EMB))[lane] = o;
}

// ---------------- Kernel B: W0 matvec + hop-2 attention + W1 ----------------
__global__ __launch_bounds__(256) void pgra_tail(
    const int* __restrict__ node, const int* __restrict__ relation,
    const int* __restrict__ adj_rela, const float* __restrict__ agg,
    const float* __restrict__ W0, const float* __restrict__ b0,
    const float* __restrict__ W1, const float* __restrict__ b1,
    const float* __restrict__ costab, float* __restrict__ out)
{
    const int b   = blockIdx.x;
    const int tid = threadIdx.x;

    __shared__ float s_agg[KN][EMB];
    __shared__ float s_h1[KN][EMB];
    __shared__ float s_cos[NREL];
    __shared__ int   s_r0[KN];
    __shared__ float s_fin[EMB];

    const int n0  = node[b];
    const int rel = relation[b];

    // coalesced load of this b's 16x128 agg tile (2048 floats = 512 float4)
    {
        const float4* ap = (const float4*)(agg + (size_t)b * KN * EMB);
        float4* sp = (float4*)&s_agg[0][0];
        sp[tid]       = ap[tid];
        sp[tid + 256] = ap[tid + 256];
    }
    if (tid < NREL) s_cos[tid] = costab[tid * NREL + rel];
    if (tid < KN)   s_r0[tid]  = adj_rela[n0 * KN + tid];
    __syncthreads();

    // Phase 2: h1[j] = tanh(agg[j] @ W0 + b0), j-group batching for W0 reuse.
    {
        const int e  = tid & 127;
        const int jg = (tid >> 7) * 8;
        float acc[8];
        const float bias = b0[e];
        #pragma unroll
        for (int q = 0; q < 8; ++q) acc[q] = bias;
        for (int ee4 = 0; ee4 < EMB / 4; ++ee4) {
            const float w0v = W0[(4 * ee4 + 0) * EMB + e];
            const float w1v = W0[(4 * ee4 + 1) * EMB + e];
            const float w2v = W0[(4 * ee4 + 2) * EMB + e];
            const float w3v = W0[(4 * ee4 + 3) * EMB + e];
            #pragma unroll
            for (int q = 0; q < 8; ++q) {
                const float4 a = *(const float4*)&s_agg[jg + q][4 * ee4];
                acc[q] = fmaf(a.x, w0v, fmaf(a.y, w1v, fmaf(a.z, w2v, fmaf(a.w, w3v, acc[q]))));
            }
        }
        #pragma unroll
        for (int q = 0; q < 8; ++q) s_h1[jg + q][e] = tanhf(acc[q]);
    }
    __syncthreads();

    // Phase 3: hop-2 attention over the 16 h1 vectors.
    if (tid < EMB) {
        float sc0[KN];
        float m = -1e30f;
        #pragma unroll
        for (int k = 0; k < KN; ++k) { sc0[k] = s_cos[s_r0[k]]; m = fmaxf(m, sc0[k]); }
        float sum = 0.f;
        #pragma unroll
        for (int k = 0; k < KN; ++k) { sc0[k] = __expf(sc0[k] - m); sum += sc0[k]; }
        const float inv = 1.f / sum;
        float a = 0.f;
        #pragma unroll
        for (int k = 0; k < KN; ++k) a = fmaf(sc0[k], s_h1[k][tid], a);
        s_fin[tid] = a * inv;
    }
    __syncthreads();

    // Phase 4: out = tanh(fin @ W1 + b1)
    if (tid < EMB) {
        float acc = b1[tid];
        for (int ee = 0; ee < EMB; ++ee) acc = fmaf(s_fin[ee], W1[ee * EMB + tid], acc);
        out[(size_t)b * EMB + tid] = tanhf(acc);
    }
}

// ---------------- Fallback fused kernel (round-1 verified) ------------------
__global__ __launch_bounds__(256) void pgra_main(
    const int* __restrict__ node, const int* __restrict__ relation,
    const int* __restrict__ adj_node, const int* __restrict__ adj_rela,
    const float* __restrict__ node_table, const float* __restrict__ proj_table,
    const float* __restrict__ W0, const float* __restrict__ b0,
    const float* __restrict__ W1, const float* __restrict__ b1,
    const float* __restrict__ costab, float* __restrict__ out)
{
    const int b    = blockIdx.x;
    const int tid  = threadIdx.x;
    const int wave = tid >> 6;
    const int lane = tid & 63;

    __shared__ float s_proj[EMB];
    __shared__ float s_cos[NREL];
    __shared__ int   s_n1[KN];
    __shared__ int   s_r0[KN];
    __shared__ float s_agg[KN][EMB];
    __shared__ float s_h1[KN][EMB];
    __shared__ float s_fin[EMB];

    const int n0  = node[b];
    const int rel = relation[b];
    if (tid < EMB)  s_proj[tid] = proj_table[rel * EMB + tid];
    if (tid < NREL) s_cos[tid]  = costab[tid * NREL + rel];
    if (tid < KN) {
        s_n1[tid] = adj_node[n0 * KN + tid];
        s_r0[tid] = adj_rela[n0 * KN + tid];
    }
    __syncthreads();

    for (int jj = 0; jj < 4; ++jj) {
        const int j  = wave * 4 + jj;
        const int n1 = s_n1[j];
        const int4* n2p = (const int4*)(adj_node + (size_t)n1 * KN);
        const int4* r1p = (const int4*)(adj_rela + (size_t)n1 * KN);
        int   n2[KN];
        float sc[KN];
        #pragma unroll
        for (int q = 0; q < 4; ++q) {
            int4 nn = n2p[q]; int4 rr = r1p[q];
            n2[4*q+0] = nn.x; n2[4*q+1] = nn.y; n2[4*q+2] = nn.z; n2[4*q+3] = nn.w;
            sc[4*q+0] = s_cos[rr.x]; sc[4*q+1] = s_cos[rr.y];
            sc[4*q+2] = s_cos[rr.z]; sc[4*q+3] = s_cos[rr.w];
        }
        float m = sc[0];
        #pragma unroll
        for (int k = 1; k < KN; ++k) m = fmaxf(m, sc[k]);
        float sum = 0.f;
        #pragma unroll
        for (int k = 0; k < KN; ++k) { sc[k] = __expf(sc[k] - m); sum += sc[k]; }
        const float inv = 1.f / sum;
        float ax = 0.f, ay = 0.f;
        #pragma unroll
        for (int k = 0; k < KN; ++k) {
            const float2 v = ((const float2*)(node_table + (size_t)n2[k] * EMB))[lane];
            ax = fmaf(sc[k], v.x, ax);
            ay = fmaf(sc[k], v.y, ay);
        }
        s_agg[j][2*lane]   = ax * inv * s_proj[2*lane];
        s_agg[j][2*lane+1] = ay * inv * s_proj[2*lane+1];
    }
    __syncthreads();

    {
        const int e  = tid & 127;
        const int jg = (tid >> 7) * 8;
        float acc[8];
        const float bias = b0[e];
        #pragma unroll
        for (int q = 0; q < 8; ++q) acc[q] = bias;
        for (int ee = 0; ee < EMB; ++ee) {
            const float w = W0[ee * EMB + e];
            #pragma unroll
            for (int q = 0; q < 8; ++q) acc[q] = fmaf(s_agg[jg + q][ee], w, acc[q]);
        }
        #pragma unroll
        for (int q = 0; q < 8; ++q) s_h1[jg + q][e] = tanhf(acc[q]);
    }
    __syncthreads();

    if (tid < EMB) {
        float sc0[KN];
        float m = -1e30f;
        #pragma unroll
        for (int k = 0; k < KN; ++k) { sc0[k] = s_cos[s_r0[k]]; m = fmaxf(m, sc0[k]); }
        float sum = 0.f;
        #pragma unroll
        for (int k = 0; k < KN; ++k) { sc0[k] = __expf(sc0[k] - m); sum += sc0[k]; }
        const float inv = 1.f / sum;
        float a = 0.f;
        #pragma unroll
        for (int k = 0; k < KN; ++k) a = fmaf(sc0[k], s_h1[k][tid], a);
        s_fin[tid] = a * inv;
    }
    __syncthreads();

    if (tid < EMB) {
        float acc = b1[tid];
        for (int ee = 0; ee < EMB; ++ee) acc = fmaf(s_fin[ee], W1[ee * EMB + tid], acc);
        out[(size_t)b * EMB + tid] = tanhf(acc);
    }
}

extern "C" void kernel_launch(void* const* d_in, const int* in_sizes, int n_in,
                              void* d_out, int out_size, void* d_ws, size_t ws_size,
                              hipStream_t stream) {
    const int*   node       = (const int*)d_in[0];
    const int*   relation   = (const int*)d_in[1];
    const int*   adj_node   = (const int*)d_in[2];
    const int*   adj_rela   = (const int*)d_in[3];
    const float* node_table = (const float*)d_in[4];
    const float* rela_table = (const float*)d_in[5];
    const float* proj_table = (const float*)d_in[6];
    const float* W0         = (const float*)d_in[7];
    const float* b0         = (const float*)d_in[8];
    const float* W1         = (const float*)d_in[9];
    const float* b1         = (const float*)d_in[10];
    float* outp = (float*)d_out;
    const int B = in_sizes[0];

    float* costab = (float*)d_ws;                    // 1024 floats = 4 KB
    float* agg    = (float*)d_ws + 1024;             // B*16*128 floats
    const size_t need = (size_t)(1024 + (size_t)B * KN * EMB) * sizeof(float);

    hipLaunchKernelGGL(pgra_costab_k, dim3(NREL * NREL / 4), dim3(256), 0, stream,
                       rela_table, costab);

    if (ws_size >= need) {
        const int npair = B * KN;
        hipLaunchKernelGGL(pgra_gather, dim3((npair + 3) / 4), dim3(256), 0, stream,
                           node, relation, adj_node, adj_rela,
                           node_table, proj_table, costab, agg, npair);
        hipLaunchKernelGGL(pgra_tail, dim3(B), dim3(256), 0, stream,
                           node, relation, adj_rela, agg,
                           W0, b0, W1, b1, costab, outp);
    } else {
        hipLaunchKernelGGL(pgra_main, dim3(B), dim3(256), 0, stream,
                           node, relation, adj_node, adj_rela,
                           node_table, proj_table, W0, b0, W1, b1, costab, outp);
    }
}